// Round 3
// baseline (710.788 us; speedup 1.0000x reference)
//
#include <hip/hip_runtime.h>

#define SEQ 512
#define BATCH 1024
#define EMB 100
#define HID 6
#define DFF 200
#define SB (SEQ*BATCH)

// K1: pre0[s][b][0..7] = x[s][b][:] @ W_ih0^T + (b_ih0 + b_hh0), padded to 8 floats/row
__global__ __launch_bounds__(256) void pre0_kernel(
    const float* __restrict__ x, const float* __restrict__ Wih0,
    const float* __restrict__ bih0, const float* __restrict__ bhh0,
    float* __restrict__ pre0)
{
    __shared__ float wlds[6*104];   // W rows padded to 104 floats => 16B-aligned float4 reads
    __shared__ float blds[6];
    const int t = threadIdx.x;
    for (int i = t; i < 600; i += 256)
        wlds[(i/100)*104 + (i%100)] = Wih0[i];
    if (t < 6) blds[t] = bih0[t] + bhh0[t];
    __syncthreads();

    const int row0 = blockIdx.x*1024 + t;   // this thread handles rows row0 + r*256, r=0..3
    float acc[4][6];
    #pragma unroll
    for (int r=0;r<4;r++)
        #pragma unroll
        for (int h=0;h<6;h++) acc[r][h] = blds[h];

    const float4* __restrict__ x4 = (const float4*)x;
    for (int c=0;c<25;c++){
        float4 xv[4];
        #pragma unroll
        for (int r=0;r<4;r++) xv[r] = x4[(row0 + r*256)*25 + c];
        #pragma unroll
        for (int h=0;h<6;h++){
            const float4 wv = *(const float4*)&wlds[h*104 + c*4];
            #pragma unroll
            for (int r=0;r<4;r++){
                acc[r][h] += xv[r].x*wv.x;
                acc[r][h] += xv[r].y*wv.y;
                acc[r][h] += xv[r].z*wv.z;
                acc[r][h] += xv[r].w*wv.w;
            }
        }
    }

    float4* __restrict__ p4 = (float4*)pre0;
    #pragma unroll
    for (int r=0;r<4;r++){
        const int row = row0 + r*256;
        p4[row*2+0] = make_float4(acc[r][0],acc[r][1],acc[r][2],acc[r][3]);
        p4[row*2+1] = make_float4(acc[r][4],acc[r][5],0.f,0.f);
    }
}

// K2: sequential 512-step two-layer ReLU RNN scan + folded linear-linear head.
__global__ __launch_bounds__(64) void scan_kernel(
    const float* __restrict__ pre0,
    const float* __restrict__ Whh0, const float* __restrict__ Wih1,
    const float* __restrict__ Whh1, const float* __restrict__ bih1,
    const float* __restrict__ bhh1,
    const float* __restrict__ W1, const float* __restrict__ b1v,
    const float* __restrict__ W2, const float* __restrict__ b2v,
    float* __restrict__ out)
{
    const int b = blockIdx.x*64 + threadIdx.x;

    float whh0[36], wih1[36], whh1[36], bias1[6];
    #pragma unroll
    for (int i=0;i<36;i++) whh0[i]=Whh0[i];
    #pragma unroll
    for (int i=0;i<36;i++) wih1[i]=Wih1[i];
    #pragma unroll
    for (int i=0;i<36;i++) whh1[i]=Whh1[i];
    #pragma unroll
    for (int h=0;h<6;h++) bias1[h]=bih1[h]+bhh1[h];

    float h0[6]={0,0,0,0,0,0}, h1[6]={0,0,0,0,0,0};

    const float4* __restrict__ p4 = (const float4*)pre0;
    float4 pa0 = p4[b*2+0], pa1 = p4[b*2+1];

    for (int s=0;s<SEQ;s++){
        float4 pb0 = pa0, pb1 = pa1;
        if (s+1 < SEQ){
            const int nrow = (s+1)*BATCH + b;
            pb0 = p4[nrow*2+0]; pb1 = p4[nrow*2+1];
        }
        const float p[6] = {pa0.x,pa0.y,pa0.z,pa0.w,pa1.x,pa1.y};

        float h0n[6];
        #pragma unroll
        for (int h=0;h<6;h++){
            float a = p[h];
            #pragma unroll
            for (int j=0;j<6;j++) a += whh0[h*6+j]*h0[j];
            h0n[h] = fmaxf(a, 0.f);
        }
        float h1n[6];
        #pragma unroll
        for (int h=0;h<6;h++){
            float a = bias1[h];
            #pragma unroll
            for (int j=0;j<6;j++) a += wih1[h*6+j]*h0n[j];
            #pragma unroll
            for (int j=0;j<6;j++) a += whh1[h*6+j]*h1[j];
            h1n[h] = fmaxf(a, 0.f);
        }
        #pragma unroll
        for (int h=0;h<6;h++){ h0[h]=h0n[h]; h1[h]=h1n[h]; }
        pa0=pb0; pa1=pb1;
    }

    // Head is linear-linear => collapses: out = h1 @ (W2*W1)^T + (W2*b1 + b2).
    // Computed directly per-thread (1600 FMA, ~1.3us) instead of an extra kernel.
    float o0 = b2v[0], o1 = b2v[1];
    for (int f=0; f<DFF; f++){
        float hf = b1v[f];
        #pragma unroll
        for (int h=0;h<6;h++) hf += W1[f*6+h]*h1[h];
        o0 += W2[f]*hf;
        o1 += W2[DFF+f]*hf;
    }
    out[b*2+0]=o0; out[b*2+1]=o1;
}

extern "C" void kernel_launch(void* const* d_in, const int* in_sizes, int n_in,
                              void* d_out, int out_size, void* d_ws, size_t ws_size,
                              hipStream_t stream)
{
    const float* x    = (const float*)d_in[0];
    const float* Wih0 = (const float*)d_in[1];
    const float* Whh0 = (const float*)d_in[2];
    const float* bih0 = (const float*)d_in[3];
    const float* bhh0 = (const float*)d_in[4];
    const float* Wih1 = (const float*)d_in[5];
    const float* Whh1 = (const float*)d_in[6];
    const float* bih1 = (const float*)d_in[7];
    const float* bhh1 = (const float*)d_in[8];
    const float* W1   = (const float*)d_in[9];
    const float* b1v  = (const float*)d_in[10];
    const float* W2   = (const float*)d_in[11];
    const float* b2v  = (const float*)d_in[12];
    float* out  = (float*)d_out;
    float* pre0 = (float*)d_ws;   // SB * 8 floats = 16 MiB

    pre0_kernel<<<SB/1024, 256, 0, stream>>>(x, Wih0, bih0, bhh0, pre0);
    scan_kernel<<<BATCH/64, 64, 0, stream>>>(pre0, Whh0, Wih1, Whh1, bih1, bhh1,
                                             W1, b1v, W2, b2v, out);
}

// Round 5
// 562.548 us; speedup vs baseline: 1.2635x; 1.2635x over previous
//
#include <hip/hip_runtime.h>

#define SEQ 512
#define BATCH 1024
#define EMB 100
#define HID 6
#define DFF 200
#define SB (SEQ*BATCH)

// K1: pre0[row][0..7] = x[row][:] @ W_ih0^T + (b_ih0+b_hh0), row = s*BATCH+b.
// 1-wave blocks; 64 rows staged coalesced into LDS, then per-lane-row compute.
// LDS row stride = 25 float4 -> bank group (l+c)%8 -> even spread (b128 floor).
__global__ __launch_bounds__(64) void pre0_kernel(
    const float* __restrict__ x, const float* __restrict__ Wih0,
    const float* __restrict__ bih0, const float* __restrict__ bhh0,
    float* __restrict__ pre0)
{
    __shared__ float4 xlds[64*25];   // 25.6 KB: 64 rows x 100 floats
    __shared__ float4 wlds[6*25];    // 2.4 KB: W_ih0 as [6][25] float4
    __shared__ float  blds[8];

    const int lane = threadIdx.x;
    const int rowbase = blockIdx.x * 64;

    // stage W (wave-uniform broadcast reads later) and bias
    const float4* __restrict__ wg4 = (const float4*)Wih0;
    #pragma unroll
    for (int k = 0; k < 3; k++){
        int i = lane + 64*k;
        if (i < 150) wlds[i] = wg4[i];
    }
    if (lane < 6) blds[lane] = bih0[lane] + bhh0[lane];

    // stage 64 rows of x, fully coalesced: 1600 float4, 25 per lane
    const float4* __restrict__ x4 = (const float4*)x;
    const size_t gbase = (size_t)rowbase * 25;
    #pragma unroll
    for (int k = 0; k < 25; k++)
        xlds[lane + 64*k] = x4[gbase + lane + 64*k];

    __syncthreads();   // single wave: compiles to a waitcnt, keeps LDS ordering safe

    float acc[6];
    #pragma unroll
    for (int h = 0; h < 6; h++) acc[h] = blds[h];

    #pragma unroll
    for (int c = 0; c < 25; c++){
        const float4 xv = xlds[lane*25 + c];
        #pragma unroll
        for (int h = 0; h < 6; h++){
            const float4 wv = wlds[h*25 + c];
            acc[h] += xv.x*wv.x;
            acc[h] += xv.y*wv.y;
            acc[h] += xv.z*wv.z;
            acc[h] += xv.w*wv.w;
        }
    }

    float4* __restrict__ p4 = (float4*)pre0;
    const int row = rowbase + lane;
    p4[row*2+0] = make_float4(acc[0],acc[1],acc[2],acc[3]);
    p4[row*2+1] = make_float4(acc[4],acc[5],0.f,0.f);
}

// K2: sequential 512-step two-layer ReLU RNN scan + folded linear-linear head.
// Depth-4 static register prefetch pipeline (8 dwordx4 in flight, ~920 cyc ahead).
__global__ __launch_bounds__(64) void scan_kernel(
    const float* __restrict__ pre0,
    const float* __restrict__ Whh0, const float* __restrict__ Wih1,
    const float* __restrict__ Whh1, const float* __restrict__ bih1,
    const float* __restrict__ bhh1,
    const float* __restrict__ W1, const float* __restrict__ b1v,
    const float* __restrict__ W2, const float* __restrict__ b2v,
    float* __restrict__ out)
{
    const int b = blockIdx.x*64 + threadIdx.x;

    float whh0[36], wih1[36], whh1[36], bias1[6];
    #pragma unroll
    for (int i=0;i<36;i++) whh0[i]=Whh0[i];
    #pragma unroll
    for (int i=0;i<36;i++) wih1[i]=Wih1[i];
    #pragma unroll
    for (int i=0;i<36;i++) whh1[i]=Whh1[i];
    #pragma unroll
    for (int h=0;h<6;h++) bias1[h]=bih1[h]+bhh1[h];

    float h0[6]={0,0,0,0,0,0}, h1[6]={0,0,0,0,0,0};

    const float4* __restrict__ p4 = (const float4*)pre0;

    // prefetch pipeline, depth 4 (statically indexed -> stays in VGPRs)
    float4 pf0[4], pf1[4];
    #pragma unroll
    for (int k=0;k<4;k++){
        const int r = k*BATCH + b;
        pf0[k] = p4[r*2+0];
        pf1[k] = p4[r*2+1];
    }

    for (int s=0; s<SEQ; s+=4){
        #pragma unroll
        for (int u=0;u<4;u++){
            const float4 c0 = pf0[u], c1 = pf1[u];
            const int ns = s + u + 4;
            if (ns < SEQ){
                const int r = ns*BATCH + b;
                pf0[u] = p4[r*2+0];
                pf1[u] = p4[r*2+1];
            }
            const float p[6] = {c0.x,c0.y,c0.z,c0.w,c1.x,c1.y};

            float h0n[6];
            #pragma unroll
            for (int h=0;h<6;h++){
                float a = p[h];
                #pragma unroll
                for (int j=0;j<6;j++) a += whh0[h*6+j]*h0[j];
                h0n[h] = fmaxf(a, 0.f);
            }
            float h1n[6];
            #pragma unroll
            for (int h=0;h<6;h++){
                float a = bias1[h];
                #pragma unroll
                for (int j=0;j<6;j++) a += wih1[h*6+j]*h0n[j];
                #pragma unroll
                for (int j=0;j<6;j++) a += whh1[h*6+j]*h1[j];
                h1n[h] = fmaxf(a, 0.f);
            }
            #pragma unroll
            for (int h=0;h<6;h++){ h0[h]=h0n[h]; h1[h]=h1n[h]; }
        }
    }

    // Head is linear-linear => collapses: out = h1 @ (W2*W1)^T + (W2*b1 + b2).
    float o0 = b2v[0], o1 = b2v[1];
    for (int f=0; f<DFF; f++){
        float hf = b1v[f];
        #pragma unroll
        for (int h=0;h<6;h++) hf += W1[f*6+h]*h1[h];
        o0 += W2[f]*hf;
        o1 += W2[DFF+f]*hf;
    }
    out[b*2+0]=o0; out[b*2+1]=o1;
}

extern "C" void kernel_launch(void* const* d_in, const int* in_sizes, int n_in,
                              void* d_out, int out_size, void* d_ws, size_t ws_size,
                              hipStream_t stream)
{
    const float* x    = (const float*)d_in[0];
    const float* Wih0 = (const float*)d_in[1];
    const float* Whh0 = (const float*)d_in[2];
    const float* bih0 = (const float*)d_in[3];
    const float* bhh0 = (const float*)d_in[4];
    const float* Wih1 = (const float*)d_in[5];
    const float* Whh1 = (const float*)d_in[6];
    const float* bih1 = (const float*)d_in[7];
    const float* bhh1 = (const float*)d_in[8];
    const float* W1   = (const float*)d_in[9];
    const float* b1v  = (const float*)d_in[10];
    const float* W2   = (const float*)d_in[11];
    const float* b2v  = (const float*)d_in[12];
    float* out  = (float*)d_out;
    float* pre0 = (float*)d_ws;   // SB * 8 floats = 16 MiB

    pre0_kernel<<<SB/64, 64, 0, stream>>>(x, Wih0, bih0, bhh0, pre0);
    scan_kernel<<<BATCH/64, 64, 0, stream>>>(pre0, Whh0, Wih1, Whh1, bih1, bhh1,
                                             W1, b1v, W2, b2v, out);
}

// Round 8
// 540.619 us; speedup vs baseline: 1.3148x; 1.0406x over previous
//
#include <hip/hip_runtime.h>

#define SEQ 512
#define BATCH 1024
#define EMB 100
#define HID 6
#define DFF 200
#define SB (SEQ*BATCH)

typedef __attribute__((address_space(1))) void gvoid;
typedef __attribute__((address_space(3))) void lvoid;

// K1: pre0[row][0..7] = x[row][:] @ W_ih0^T + (b_ih0+b_hh0), row = s*BATCH+b.
// 1-wave blocks; 64 rows staged into LDS via global_load_lds width=16
// (fire-and-forget, no VGPR round-trip), then per-lane-row compute.
__global__ __launch_bounds__(64) void pre0_kernel(
    const float* __restrict__ x, const float* __restrict__ Wih0,
    const float* __restrict__ bih0, const float* __restrict__ bhh0,
    float* __restrict__ pre0)
{
    __shared__ float4 xlds[64*25];   // 25.6 KB: 64 rows x 100 floats
    __shared__ float4 wlds[6*25];    // 2.4 KB: W_ih0 as [6][25] float4
    __shared__ float  blds[8];

    const int lane = threadIdx.x;
    const int rowbase = blockIdx.x * 64;

    // stage 64 rows of x direct-to-LDS: lds dest = uniform base + lane*16 (linear),
    // global src per-lane coalesced. 25 loads in flight, one drain at the barrier.
    const float4* __restrict__ x4 = (const float4*)x;
    const size_t gbase = (size_t)rowbase * 25;
    #pragma unroll
    for (int k = 0; k < 25; k++){
        const float4* gp = x4 + gbase + lane + 64*k;
        __builtin_amdgcn_global_load_lds((gvoid*)gp, (lvoid*)&xlds[64*k], 16, 0, 0);
    }

    // stage W (broadcast reads later) and bias via regular path (tiny)
    const float4* __restrict__ wg4 = (const float4*)Wih0;
    #pragma unroll
    for (int k = 0; k < 3; k++){
        int i = lane + 64*k;
        if (i < 150) wlds[i] = wg4[i];
    }
    if (lane < 6) blds[lane] = bih0[lane] + bhh0[lane];

    __syncthreads();   // drains vmcnt/lgkmcnt (single wave)

    float acc[6];
    #pragma unroll
    for (int h = 0; h < 6; h++) acc[h] = blds[h];

    #pragma unroll
    for (int c = 0; c < 25; c++){
        const float4 xv = xlds[lane*25 + c];   // bank group (lane+c)%8 -> BW floor
        #pragma unroll
        for (int h = 0; h < 6; h++){
            const float4 wv = wlds[h*25 + c];
            acc[h] += xv.x*wv.x;
            acc[h] += xv.y*wv.y;
            acc[h] += xv.z*wv.z;
            acc[h] += xv.w*wv.w;
        }
    }

    float4* __restrict__ p4 = (float4*)pre0;
    const int row = rowbase + lane;
    p4[row*2+0] = make_float4(acc[0],acc[1],acc[2],acc[3]);
    p4[row*2+1] = make_float4(acc[4],acc[5],0.f,0.f);
}

// K2: sequential 512-step two-layer ReLU RNN scan + folded linear-linear head.
// Depth-8 register ring pinned with volatile asm loads; counted
// s_waitcnt vmcnt(14) + sched_barrier(0) (rule #18) before each consume.
// 8-step lookahead (~2000 cyc) covers HBM/L3 latency (~900 cyc).
__global__ __launch_bounds__(64) void scan_kernel(
    const float* __restrict__ pre0,
    const float* __restrict__ Whh0, const float* __restrict__ Wih1,
    const float* __restrict__ Whh1, const float* __restrict__ bih1,
    const float* __restrict__ bhh1,
    const float* __restrict__ W1, const float* __restrict__ b1v,
    const float* __restrict__ W2, const float* __restrict__ b2v,
    float* __restrict__ out)
{
    const int b = blockIdx.x*64 + threadIdx.x;

    float whh0[36], wih1[36], whh1[36], bias1[6];
    #pragma unroll
    for (int i=0;i<36;i++) whh0[i]=Whh0[i];
    #pragma unroll
    for (int i=0;i<36;i++) wih1[i]=Wih1[i];
    #pragma unroll
    for (int i=0;i<36;i++) whh1[i]=Whh1[i];
    #pragma unroll
    for (int h=0;h<6;h++) bias1[h]=bih1[h]+bhh1[h];

    float h0[6]={0,0,0,0,0,0}, h1[6]={0,0,0,0,0,0};

    const float4* __restrict__ p4 = (const float4*)pre0;

    auto step = [&](const float4& c0, const float4& c1){
        const float p[6] = {c0.x,c0.y,c0.z,c0.w,c1.x,c1.y};
        float h0n[6];
        #pragma unroll
        for (int h=0;h<6;h++){
            float a = p[h];
            #pragma unroll
            for (int j=0;j<6;j++) a += whh0[h*6+j]*h0[j];
            h0n[h] = fmaxf(a, 0.f);
        }
        float h1n[6];
        #pragma unroll
        for (int h=0;h<6;h++){
            float a = bias1[h];
            #pragma unroll
            for (int j=0;j<6;j++) a += wih1[h*6+j]*h0n[j];
            #pragma unroll
            for (int j=0;j<6;j++) a += whh1[h*6+j]*h1[j];
            h1n[h] = fmaxf(a, 0.f);
        }
        #pragma unroll
        for (int h=0;h<6;h++){ h0[h]=h0n[h]; h1[h]=h1n[h]; }
    };

    float4 r0[8], r1[8];   // statically indexed ring -> VGPRs (rule #20)

    // prologue: fill ring for steps 0..7
    #pragma unroll
    for (int k=0;k<8;k++){
        const float4* a = p4 + ((size_t)(k*BATCH + b))*2;
        asm volatile("global_load_dwordx4 %0, %2, off\n\t"
                     "global_load_dwordx4 %1, %2, off offset:16"
                     : "=&v"(r0[k]), "=&v"(r1[k])
                     : "v"(a)
                     : "memory");
    }

    // main: consume steps 0..503, each refills slot for step s+u+8 (8..511)
    for (int s=0; s<SEQ-8; s+=8){
        #pragma unroll
        for (int u=0;u<8;u++){
            // steady state: 16 of our loads outstanding; wait till 14 ->
            // the 2 oldest (this slot's pair) have landed. In-order retire
            // means stray compiler vmem ops only increase the drain (safe).
            asm volatile("s_waitcnt vmcnt(14)" ::: "memory");
            __builtin_amdgcn_sched_barrier(0);
            const float4 c0 = r0[u], c1 = r1[u];
            step(c0, c1);
            const float4* a = p4 + ((size_t)((s+u+8)*BATCH + b))*2;
            asm volatile("global_load_dwordx4 %0, %2, off\n\t"
                         "global_load_dwordx4 %1, %2, off offset:16"
                         : "=&v"(r0[u]), "=&v"(r1[u])
                         : "v"(a)
                         : "memory");
        }
    }

    // tail: drain once, consume steps 504..511
    asm volatile("s_waitcnt vmcnt(0)" ::: "memory");
    __builtin_amdgcn_sched_barrier(0);
    #pragma unroll
    for (int u=0;u<8;u++) step(r0[u], r1[u]);

    // Head is linear-linear => collapses: out = h1 @ (W2*W1)^T + (W2*b1 + b2).
    float o0 = b2v[0], o1 = b2v[1];
    for (int f=0; f<DFF; f++){
        float hf = b1v[f];
        #pragma unroll
        for (int h=0;h<6;h++) hf += W1[f*6+h]*h1[h];
        o0 += W2[f]*hf;
        o1 += W2[DFF+f]*hf;
    }
    out[b*2+0]=o0; out[b*2+1]=o1;
}

extern "C" void kernel_launch(void* const* d_in, const int* in_sizes, int n_in,
                              void* d_out, int out_size, void* d_ws, size_t ws_size,
                              hipStream_t stream)
{
    const float* x    = (const float*)d_in[0];
    const float* Wih0 = (const float*)d_in[1];
    const float* Whh0 = (const float*)d_in[2];
    const float* bih0 = (const float*)d_in[3];
    const float* bhh0 = (const float*)d_in[4];
    const float* Wih1 = (const float*)d_in[5];
    const float* Whh1 = (const float*)d_in[6];
    const float* bih1 = (const float*)d_in[7];
    const float* bhh1 = (const float*)d_in[8];
    const float* W1   = (const float*)d_in[9];
    const float* b1v  = (const float*)d_in[10];
    const float* W2   = (const float*)d_in[11];
    const float* b2v  = (const float*)d_in[12];
    float* out  = (float*)d_out;
    float* pre0 = (float*)d_ws;   // SB * 8 floats = 16 MiB

    pre0_kernel<<<SB/64, 64, 0, stream>>>(x, Wih0, bih0, bhh0, pre0);
    scan_kernel<<<BATCH/64, 64, 0, stream>>>(pre0, Whh0, Wih1, Whh1, bih1, bhh1,
                                             W1, b1v, W2, b2v, out);
}